// Round 5
// baseline (218.885 us; speedup 1.0000x reference)
//
#include <hip/hip_runtime.h>

// Problem constants (b=2, c=64, h=w=96)
#define NPOS 9216
#define NB 2
#define CCH 64
#define JSPLIT 8
#define JCHUNK (NPOS / JSPLIT)   // 1152
#define NSTEP (JCHUNK / 64)      // 18

typedef __attribute__((ext_vector_type(8))) short short8;
typedef __attribute__((ext_vector_type(4))) float f32x4;

#define LOG2E 1.4426950408889634f

// f32 -> bf16 bits, round-to-nearest-even (cold paths)
__device__ __forceinline__ ushort f2bf(float x) {
    unsigned u = __builtin_bit_cast(unsigned, x);
    u += 0x7FFFu + ((u >> 16) & 1u);
    return (ushort)(u >> 16);
}

__device__ __forceinline__ unsigned cvt_pk_bf16(float lo, float hi) {
    unsigned r;
    asm("v_cvt_pk_bf16_f32 %0, %1, %2" : "=v"(r) : "v"(lo), "v"(hi));
    return r;
}

// ---------------------------------------------------------------------------
// K1: 1x1 convs. q (pre-scaled by log2e),k -> bf16 [b][n][8];
// vT -> bf16 [b][c][n] UNSCALED; out[b][c][n] = Y (residual base).
// Block = 256 thr = 64 positions x 4 c-slices; 288 blocks.
// ---------------------------------------------------------------------------
__global__ __launch_bounds__(256) void qkv_kernel(
    const float* __restrict__ X, const float* __restrict__ Y,
    const float* __restrict__ Wq, const float* __restrict__ bq,
    const float* __restrict__ Wk, const float* __restrict__ bk,
    const float* __restrict__ Wv, const float* __restrict__ bv,
    ushort* __restrict__ qb, ushort* __restrict__ kb,
    ushort* __restrict__ vT, float* __restrict__ out)
{
    __shared__ float wqkT[1024];   // [c][16]: o<8 Wq, o>=8 Wk
    __shared__ float wvTs[4096];   // [c][64]
    int tid = threadIdx.x;
    for (int idx = tid; idx < 1024; idx += 256) {
        int c = idx >> 4, o = idx & 15;
        wqkT[idx] = (o < 8) ? Wq[o * 64 + c] : Wk[(o - 8) * 64 + c];
    }
    for (int idx = tid; idx < 4096; idx += 256) {
        int c = idx >> 6, o = idx & 63;
        wvTs[idx] = Wv[o * 64 + c];
    }
    __syncthreads();

    int p = tid & 63, s = tid >> 6;          // s is wave-uniform
    int base = blockIdx.x * 64;
    int b = base / NPOS;
    int n = (base % NPOS) + p;

    float va[16], qk[8];
    #pragma unroll
    for (int o = 0; o < 16; ++o) va[o] = bv[s * 16 + o];
    #pragma unroll
    for (int o = 0; o < 8; ++o) qk[o] = 0.f;
    if (s == 0) {
        #pragma unroll
        for (int o = 0; o < 8; ++o) qk[o] = bq[o];
    } else if (s == 1) {
        #pragma unroll
        for (int o = 0; o < 8; ++o) qk[o] = bk[o];
    }

    const float* Xb = X + (size_t)b * CCH * NPOS + n;
    const float* Yb = Y + (size_t)b * CCH * NPOS + n;
    float* ob = out + (size_t)b * CCH * NPOS + n;
    for (int c = 0; c < 64; ++c) {
        float yv = Yb[(size_t)c * NPOS];
        ob[(size_t)c * NPOS] = yv;                 // residual base
        const float4* wv4 = (const float4*)(wvTs + c * 64 + s * 16);
        #pragma unroll
        for (int o4 = 0; o4 < 4; ++o4) {
            float4 wv = wv4[o4];
            va[o4*4+0] += wv.x * yv; va[o4*4+1] += wv.y * yv;
            va[o4*4+2] += wv.z * yv; va[o4*4+3] += wv.w * yv;
        }
        if (s < 2) {
            float xv = Xb[(size_t)c * NPOS];
            const float4* wq4 = (const float4*)(wqkT + c * 16 + s * 8);
            float4 w0 = wq4[0], w1 = wq4[1];
            qk[0] += w0.x * xv; qk[1] += w0.y * xv;
            qk[2] += w0.z * xv; qk[3] += w0.w * xv;
            qk[4] += w1.x * xv; qk[5] += w1.y * xv;
            qk[6] += w1.z * xv; qk[7] += w1.w * xv;
        }
    }
    ushort* vdst = vT + (size_t)b * CCH * NPOS + n;
    #pragma unroll
    for (int o = 0; o < 16; ++o)
        vdst[(size_t)(s * 16 + o) * NPOS] = f2bf(va[o]);
    if (s < 2) {
        if (s == 0) {   // q: fold log2e so both passes use raw exp2
            #pragma unroll
            for (int o = 0; o < 8; ++o) qk[o] *= LOG2E;
        }
        short8 row;
        #pragma unroll
        for (int o = 0; o < 8; ++o) row[o] = (short)f2bf(qk[o]);
        ushort* dst = (s == 0 ? qb : kb) + ((size_t)b * NPOS + n) * 8;
        *(short8*)dst = row;
    }
}

// ---------------------------------------------------------------------------
// K2: Z[b][j] = sum_i exp2(q_i . k_j) via MFMA (q carries the log2e).
// grid (144 j64-blocks, 4 i-quarters, b); atomicAdd partials.
// ---------------------------------------------------------------------------
__global__ __launch_bounds__(256) void zpass_kernel(
    const ushort* __restrict__ qb, const ushort* __restrict__ kb,
    float* __restrict__ Z)
{
    int tid = threadIdx.x;
    int w = tid >> 6, l = tid & 63;
    int il = l & 15, g = l >> 4;
    int b = blockIdx.z;
    int jb = blockIdx.x * 64 + w * 16;
    const short8 zero8 = {0,0,0,0,0,0,0,0};
    const f32x4 cz = {0.f,0.f,0.f,0.f};

    short8 kf = zero8;
    if (g == 0) kf = *(const short8*)(kb + ((size_t)b * NPOS + jb + il) * 8);

    float za[4] = {0.f, 0.f, 0.f, 0.f};
    const ushort* qrow = qb + ((size_t)b * NPOS + blockIdx.y * 2304 + il) * 8;
    #pragma unroll 4
    for (int is = 0; is < 144; ++is) {
        short8 qf = *(const short8*)(qrow + (size_t)is * 128);
        if (g != 0) qf = zero8;
        f32x4 sv = __builtin_amdgcn_mfma_f32_16x16x32_bf16(kf, qf, cz, 0, 0, 0);
        za[0] += __builtin_amdgcn_exp2f(sv[0]);
        za[1] += __builtin_amdgcn_exp2f(sv[1]);
        za[2] += __builtin_amdgcn_exp2f(sv[2]);
        za[3] += __builtin_amdgcn_exp2f(sv[3]);
    }
    #pragma unroll
    for (int r = 0; r < 4; ++r) {
        float x = za[r];
        x += __shfl_xor(x, 1, 16);
        x += __shfl_xor(x, 2, 16);
        x += __shfl_xor(x, 4, 16);
        x += __shfl_xor(x, 8, 16);
        za[r] = x;
    }
    if (il == 0) {
        #pragma unroll
        for (int r = 0; r < 4; ++r)
            atomicAdd(&Z[(size_t)b * NPOS + jb + g * 4 + r], za[r]);
    }
}

// K2.5: rz = 1/Z
__global__ __launch_bounds__(256) void recipz_kernel(
    const float* __restrict__ Z, float* __restrict__ rz)
{
    int i = blockIdx.x * 256 + threadIdx.x;
    rz[i] = __builtin_amdgcn_rcpf(Z[i]);
}

// ---------------------------------------------------------------------------
// K3: X^T[c][i] += sum_j (exp2(q_i.k_j)*rz[j]) * vT[c][j], MFMA both GEMMs.
// 4 waves x 32 i = 128 i per block; KVBLK=64 -> 18 steps; vz tile [64c][64j]
// XOR-slot-swizzled + double-buffered; P via XOR-swizzled per-wave LDS;
// K reg-prefetched one step ahead. grid (72, 8, 2); atomicAdd into Y-preloaded out.
// ---------------------------------------------------------------------------
__global__ __launch_bounds__(256) void pass2_kernel(
    const ushort* __restrict__ qb, const ushort* __restrict__ kb,
    const ushort* __restrict__ vT, const float* __restrict__ rz,
    float* __restrict__ out)
{
    __shared__ ushort vz_lds[2][64 * 64];   // [64 c][8 slots of 8 j], slot^=(c&7)
    __shared__ ushort p_lds[4][32 * 64];    // per-wave [32 i][8 slots], slot^=(i&7)
    int tid = threadIdx.x;
    int w = tid >> 6, l = tid & 63;
    int il = l & 15, g = l >> 4;
    int b = blockIdx.z;
    int ibase = blockIdx.x * 128 + w * 32;
    int j0 = blockIdx.y * JCHUNK;

    const short8 zero8 = {0,0,0,0,0,0,0,0};
    const f32x4 cz = {0.f,0.f,0.f,0.f};

    short8 qf0 = zero8, qf1 = zero8;
    if (g == 0) {
        qf0 = *(const short8*)(qb + ((size_t)b * NPOS + ibase + il) * 8);
        qf1 = *(const short8*)(qb + ((size_t)b * NPOS + ibase + 16 + il) * 8);
    }

    f32x4 acc[2][4];
    #pragma unroll
    for (int h = 0; h < 2; ++h)
        #pragma unroll
        for (int cg = 0; cg < 4; ++cg) acc[h][cg] = cz;

    const ushort* kbb = kb + (size_t)b * NPOS * 8;
    const float* rzb = rz + (size_t)b * NPOS;

    // vz staging: thread -> (c-row sr, logical chunks sq & sq+4)
    int sr = tid >> 2, sq = tid & 3;
    const ushort* vrow = vT + (size_t)b * CCH * NPOS + (size_t)sr * NPOS + j0;
    int soff0 = (sq ^ (sr & 7)) * 8;
    int soff1 = ((sq + 4) ^ (sr & 7)) * 8;
    int xr = il & 7;   // read-side XOR

    // prologue: stage tile 0, load kf for step 0
    {
        float4 ga = *(const float4*)(vrow + sq * 8);
        float4 gb = *(const float4*)(vrow + (sq + 4) * 8);
        *(float4*)&vz_lds[0][sr * 64 + soff0] = ga;
        *(float4*)&vz_lds[0][sr * 64 + soff1] = gb;
    }
    short8 kf[4];
    #pragma unroll
    for (int t = 0; t < 4; ++t)
        kf[t] = (g == 0) ? *(const short8*)(kbb + (size_t)(j0 + 16 * t + il) * 8)
                         : zero8;
    __syncthreads();

    ushort* pw = p_lds[w];

    for (int st = 0; st < NSTEP; ++st) {
        int jb = j0 + st * 64;
        int cur = st & 1;
        bool more = (st + 1) < NSTEP;

        // prefetch next K + next vz tile into regs (latency hidden under step)
        float4 g0n = {0,0,0,0}, g1n = {0,0,0,0};
        short8 kn[4] = {zero8, zero8, zero8, zero8};
        if (more) {
            int jn = (st + 1) * 64;
            g0n = *(const float4*)(vrow + jn + sq * 8);
            g1n = *(const float4*)(vrow + jn + (sq + 4) * 8);
            #pragma unroll
            for (int t = 0; t < 4; ++t)
                if (g == 0)
                    kn[t] = *(const short8*)(kbb + (size_t)(jb + 64 + 16 * t + il) * 8);
        }
        float4 rzv[4];
        #pragma unroll
        for (int t = 0; t < 4; ++t)
            rzv[t] = *(const float4*)(rzb + jb + 16 * t + 4 * g);

        // S (8 MFMA) -> P = exp2(s)*rz -> bf16 -> p_lds
        #pragma unroll
        for (int h = 0; h < 2; ++h) {
            short8 qf = h ? qf1 : qf0;
            int rowoff = (16 * h + il) * 64;
            #pragma unroll
            for (int t = 0; t < 4; ++t) {
                f32x4 sv = __builtin_amdgcn_mfma_f32_16x16x32_bf16(kf[t], qf, cz, 0, 0, 0);
                float p0 = __builtin_amdgcn_exp2f(sv[0]) * rzv[t].x;
                float p1 = __builtin_amdgcn_exp2f(sv[1]) * rzv[t].y;
                float p2 = __builtin_amdgcn_exp2f(sv[2]) * rzv[t].z;
                float p3 = __builtin_amdgcn_exp2f(sv[3]) * rzv[t].w;
                uint2 u;
                u.x = cvt_pk_bf16(p0, p1);
                u.y = cvt_pk_bf16(p2, p3);
                int stored = (2 * t + (g >> 1)) ^ xr;
                *(uint2*)&pw[rowoff + stored * 8 + (g & 1) * 4] = u;
            }
        }

        // P^T B-frags (same-wave readback, swizzled slots)
        short8 pf[2][2];
        #pragma unroll
        for (int h = 0; h < 2; ++h) {
            int rowoff = (16 * h + il) * 64;
            pf[h][0] = *(short8*)&pw[rowoff + ((g ^ xr) * 8)];
            pf[h][1] = *(short8*)&pw[rowoff + (((4 + g) ^ xr) * 8)];
        }

        // PV: 4 c-groups x 2 k-halves x 2 i-halves (16 MFMA); af shared across h
        #pragma unroll
        for (int cg = 0; cg < 4; ++cg) {
            int row = (cg * 16 + il) * 64;
            short8 af0 = *(short8*)&vz_lds[cur][row + ((g ^ xr) * 8)];
            short8 af1 = *(short8*)&vz_lds[cur][row + (((4 + g) ^ xr) * 8)];
            #pragma unroll
            for (int h = 0; h < 2; ++h) {
                acc[h][cg] = __builtin_amdgcn_mfma_f32_16x16x32_bf16(af0, pf[h][0], acc[h][cg], 0, 0, 0);
                acc[h][cg] = __builtin_amdgcn_mfma_f32_16x16x32_bf16(af1, pf[h][1], acc[h][cg], 0, 0, 0);
            }
        }

        // stage next tile; rotate K regs; one barrier per step
        if (more) {
            *(float4*)&vz_lds[cur ^ 1][sr * 64 + soff0] = g0n;
            *(float4*)&vz_lds[cur ^ 1][sr * 64 + soff1] = g1n;
            #pragma unroll
            for (int t = 0; t < 4; ++t) kf[t] = kn[t];
        }
        __syncthreads();
    }

    // epilogue: D row=c_local=g*4+r, col=i=16h+il
    float* ob = out + (size_t)b * CCH * NPOS + ibase + il;
    #pragma unroll
    for (int h = 0; h < 2; ++h)
        #pragma unroll
        for (int cg = 0; cg < 4; ++cg)
            #pragma unroll
            for (int r = 0; r < 4; ++r)
                atomicAdd(ob + (size_t)(cg * 16 + g * 4 + r) * NPOS + 16 * h,
                          acc[h][cg][r]);
}

extern "C" void kernel_launch(void* const* d_in, const int* in_sizes, int n_in,
                              void* d_out, int out_size, void* d_ws, size_t ws_size,
                              hipStream_t stream) {
    const float* X  = (const float*)d_in[0];
    const float* Y  = (const float*)d_in[1];
    const float* Wq = (const float*)d_in[2];
    const float* bq = (const float*)d_in[3];
    const float* Wk = (const float*)d_in[4];
    const float* bk = (const float*)d_in[5];
    const float* Wv = (const float*)d_in[6];
    const float* bv = (const float*)d_in[7];

    char* ws = (char*)d_ws;
    ushort* qb  = (ushort*)(ws);             // 2*9216*8 bf16   = 294912 B
    ushort* kbw = (ushort*)(ws + 294912);    // 294912 B
    ushort* vT  = (ushort*)(ws + 589824);    // 2*64*9216 bf16  = 2359296 B
    float*  Z   = (float*) (ws + 2949120);   // 18432 f32       = 73728 B
    float*  rz  = (float*) (ws + 3022848);   // 73728 B

    hipMemsetAsync(Z, 0, (size_t)NB * NPOS * sizeof(float), stream);

    qkv_kernel<<<288, 256, 0, stream>>>(X, Y, Wq, bq, Wk, bk, Wv, bv,
                                        qb, kbw, vT, (float*)d_out);
    zpass_kernel<<<dim3(144, 4, NB), 256, 0, stream>>>(qb, kbw, Z);
    recipz_kernel<<<72, 256, 0, stream>>>(Z, rz);
    pass2_kernel<<<dim3(72, JSPLIT, NB), 256, 0, stream>>>(qb, kbw, vT, rz,
                                                           (float*)d_out);
}

// Round 7
// 199.218 us; speedup vs baseline: 1.0987x; 1.0987x over previous
//
#include <hip/hip_runtime.h>

// Problem constants (b=2, c=64, h=w=96)
#define NPOS 9216
#define NB 2
#define CCH 64
#define JSPLIT 8
#define JCHUNK (NPOS / JSPLIT)   // 1152
#define NSTEP (JCHUNK / 64)      // 18

typedef __attribute__((ext_vector_type(8))) short short8;
typedef __attribute__((ext_vector_type(4))) short short4b;
typedef __attribute__((ext_vector_type(4))) float f32x4;
typedef __attribute__((ext_vector_type(16))) float f32x16;

#define LOG2E 1.4426950408889634f

// K=16 bf16 MFMA (v_mfma_f32_16x16x16_bf16; clang name is the gfx90a-era _1k).
// Guarded: amdgcn builtins don't exist in the host compile pass.
__device__ __forceinline__ f32x4 mfma16(short4b a, short4b b, f32x4 c) {
#if defined(__HIP_DEVICE_COMPILE__)
    return __builtin_amdgcn_mfma_f32_16x16x16bf16_1k(a, b, c, 0, 0, 0);
#else
    return c;
#endif
}

// f32 -> bf16 bits, round-to-nearest-even (cold paths)
__device__ __forceinline__ ushort f2bf(float x) {
    unsigned u = __builtin_bit_cast(unsigned, x);
    u += 0x7FFFu + ((u >> 16) & 1u);
    return (ushort)(u >> 16);
}

__device__ __forceinline__ unsigned cvt_pk_bf16(float lo, float hi) {
    unsigned r;
    asm("v_cvt_pk_bf16_f32 %0, %1, %2" : "=v"(r) : "v"(lo), "v"(hi));
    return r;
}

// ---------------------------------------------------------------------------
// K1: 1x1 convs. q (pre-scaled by log2e),k -> bf16 [b][n][8];
// vT -> bf16 [b][c][n] unscaled; out[b][c][n] = Y (residual base).
// Block = 256 thr = 32 positions x 8 slices (8 ch each); 576 blocks.
// ---------------------------------------------------------------------------
__global__ __launch_bounds__(256) void qkv_kernel(
    const float* __restrict__ X, const float* __restrict__ Y,
    const float* __restrict__ Wq, const float* __restrict__ bq,
    const float* __restrict__ Wk, const float* __restrict__ bk,
    const float* __restrict__ Wv, const float* __restrict__ bv,
    ushort* __restrict__ qb, ushort* __restrict__ kb,
    ushort* __restrict__ vT, float* __restrict__ out)
{
    __shared__ float wqkT[1024];   // [c][16]: o<8 Wq, o>=8 Wk
    __shared__ float wvTs[4096];   // [c][64]
    int tid = threadIdx.x;
    for (int idx = tid; idx < 1024; idx += 256) {
        int c = idx >> 4, o = idx & 15;
        wqkT[idx] = (o < 8) ? Wq[o * 64 + c] : Wk[(o - 8) * 64 + c];
    }
    for (int idx = tid; idx < 4096; idx += 256) {
        int c = idx >> 6, o = idx & 63;
        wvTs[idx] = Wv[o * 64 + c];
    }
    __syncthreads();

    int p = tid & 31, s = tid >> 5;       // s: 8-channel slice
    int base = blockIdx.x * 32;
    int b = base / NPOS;
    int n = (base % NPOS) + p;

    float va[8], qk[8], ysave[8];
    #pragma unroll
    for (int o = 0; o < 8; ++o) va[o] = bv[s * 8 + o];
    #pragma unroll
    for (int o = 0; o < 8; ++o) qk[o] = 0.f;
    if (s == 0) {
        #pragma unroll
        for (int o = 0; o < 8; ++o) qk[o] = bq[o];
    } else if (s == 1) {
        #pragma unroll
        for (int o = 0; o < 8; ++o) qk[o] = bk[o];
    }

    const float* Xb = X + (size_t)b * CCH * NPOS + n;
    const float* Yb = Y + (size_t)b * CCH * NPOS + n;
    for (int co = 0; co < 8; ++co) {
        #pragma unroll
        for (int ci = 0; ci < 8; ++ci) {
            int c = co * 8 + ci;
            float yv = Yb[(size_t)c * NPOS];
            if (co == s) ysave[ci] = yv;
            const float* wv = wvTs + c * 64 + s * 8;
            #pragma unroll
            for (int o = 0; o < 8; ++o) va[o] += wv[o] * yv;
            if (s < 2) {
                float xv = Xb[(size_t)c * NPOS];
                const float* wq = wqkT + c * 16 + s * 8;
                #pragma unroll
                for (int o = 0; o < 8; ++o) qk[o] += wq[o] * xv;
            }
        }
    }

    ushort* vdst = vT + (size_t)b * CCH * NPOS + n;
    float* ob = out + (size_t)b * CCH * NPOS + n;
    #pragma unroll
    for (int o = 0; o < 8; ++o) {
        vdst[(size_t)(s * 8 + o) * NPOS] = f2bf(va[o]);
        ob[(size_t)(s * 8 + o) * NPOS] = ysave[o];
    }
    if (s < 2) {
        if (s == 0) {   // fold log2e into q so both passes use raw exp2
            #pragma unroll
            for (int o = 0; o < 8; ++o) qk[o] *= LOG2E;
        }
        short8 row;
        #pragma unroll
        for (int o = 0; o < 8; ++o) row[o] = (short)f2bf(qk[o]);
        ushort* dst = (s == 0 ? qb : kb) + ((size_t)b * NPOS + n) * 8;
        *(short8*)dst = row;
    }
}

// ---------------------------------------------------------------------------
// K2: Z[b][j] = sum_i exp2(q_i . k_j) via 32x32x16 MFMA (K pad 8->16).
// Wave owns 32 j; streams 32-i q tiles. D: row=j=(r&3)+8(r>>2)+4h, col=i.
// grid (72 j128-blocks, 8 i-splits, b).
// ---------------------------------------------------------------------------
__global__ __launch_bounds__(256) void zpass_kernel(
    const ushort* __restrict__ qb, const ushort* __restrict__ kb,
    float* __restrict__ Z)
{
    int tid = threadIdx.x;
    int w = tid >> 6, l = tid & 63;
    int il2 = l & 31, h = l >> 5;
    int b = blockIdx.z;
    int jb = blockIdx.x * 128 + w * 32;
    int i0 = blockIdx.y * 1152;
    const short8 zero8 = {0,0,0,0,0,0,0,0};
    f32x16 cz16;
    #pragma unroll
    for (int r = 0; r < 16; ++r) cz16[r] = 0.f;

    short8 kf = zero8;
    if (h == 0) kf = *(const short8*)(kb + ((size_t)b * NPOS + jb + il2) * 8);

    f32x16 za = cz16;
    const ushort* qrow = qb + ((size_t)b * NPOS + i0 + il2) * 8;
    short8 qf = (h == 0) ? *(const short8*)qrow : zero8;
    for (int it = 0; it < 36; ++it) {
        short8 qn = zero8;
        if (h == 0 && (it + 1) < 36)
            qn = *(const short8*)(qrow + (size_t)(it + 1) * 256);
        f32x16 sv = __builtin_amdgcn_mfma_f32_32x32x16_bf16(kf, qf, cz16, 0, 0, 0);
        #pragma unroll
        for (int r = 0; r < 16; ++r) za[r] += __builtin_amdgcn_exp2f(sv[r]);
        qf = qn;
    }
    #pragma unroll
    for (int r = 0; r < 16; ++r) {
        float x = za[r];
        x += __shfl_xor(x, 1, 32);
        x += __shfl_xor(x, 2, 32);
        x += __shfl_xor(x, 4, 32);
        x += __shfl_xor(x, 8, 32);
        x += __shfl_xor(x, 16, 32);
        za[r] = x;
    }
    if (il2 == 0) {
        #pragma unroll
        for (int r = 0; r < 16; ++r) {
            int j = jb + (r & 3) + 8 * (r >> 2) + 4 * h;
            atomicAdd(&Z[(size_t)b * NPOS + j], za[r]);
        }
    }
}

// ---------------------------------------------------------------------------
// K3: X^T[c][i] += sum_j (exp2(q_i.k_j)/Z[j]) * vT[c][j].
// 4 waves SPLIT J (16 j each); PV uses 16x16x16 MFMA whose B-frag == S-output
// registers (zero cross-lane movement). vz tile [64c][64j] bf16,
// 16B-slot XOR-swizzled + double-buffered. Epilogue: 4-round LDS reduce
// across waves, then atomicAdd into Y-preloaded out.
// grid (144 i-blocks of 64, JSPLIT, b).
// ---------------------------------------------------------------------------
__global__ __launch_bounds__(256) void pass2_kernel(
    const ushort* __restrict__ qb, const ushort* __restrict__ kb,
    const ushort* __restrict__ vT, const float* __restrict__ Z,
    float* __restrict__ out)
{
    __shared__ ushort vz[2][64 * 64];   // 16 KB; rows c, 8 slots of 8 j, slot^=(c&7)
    int tid = threadIdx.x;
    int w = tid >> 6, l = tid & 63;
    int il = l & 15, g = l >> 4;
    int b = blockIdx.z;
    int ibase = blockIdx.x * 64;
    int j0 = blockIdx.y * JCHUNK;
    int jw = w * 16;                    // wave's j offset inside the 64-j step

    const short8 zero8 = {0,0,0,0,0,0,0,0};
    const f32x4 cz = {0.f,0.f,0.f,0.f};

    short8 qf[4];
    #pragma unroll
    for (int it = 0; it < 4; ++it) {
        qf[it] = zero8;
        if (g == 0)
            qf[it] = *(const short8*)(qb + ((size_t)b * NPOS + ibase + it * 16 + il) * 8);
    }

    f32x4 acc[4][4];
    #pragma unroll
    for (int cg = 0; cg < 4; ++cg)
        #pragma unroll
        for (int it = 0; it < 4; ++it) acc[cg][it] = cz;

    const ushort* kbb = kb + (size_t)b * NPOS * 8;
    const float* Zb = Z + (size_t)b * NPOS;

    // staging: thread -> row sr (64 rows), slot quads sq and sq+4
    int sr = tid >> 2, sq = tid & 3;
    const ushort* vrow = vT + (size_t)b * CCH * NPOS + (size_t)sr * NPOS + j0;
    int so0 = (sq ^ (sr & 7)) * 8;
    int so1 = ((sq + 4) ^ (sr & 7)) * 8;

    // prologue: stage tile 0, prefetch step-0 K and Z
    {
        float4 ga = *(const float4*)(vrow + sq * 8);
        float4 gb = *(const float4*)(vrow + sq * 8 + 32);
        *(float4*)&vz[0][sr * 64 + so0] = ga;
        *(float4*)&vz[0][sr * 64 + so1] = gb;
    }
    short8 kf = zero8;
    if (g == 0) kf = *(const short8*)(kbb + (size_t)(j0 + jw + il) * 8);
    float4 Zv = *(const float4*)(Zb + j0 + jw + 4 * g);
    __syncthreads();

    int rslot = 2 * w + (g >> 1);   // wave's 16B slot on the read side
    int rbyte = (g & 1) * 4;        // ushort offset within slot

    for (int st = 0; st < NSTEP; ++st) {
        int cur = st & 1;
        bool more = (st + 1) < NSTEP;

        float4 ga = {0,0,0,0}, gb = {0,0,0,0}, Zn = {0,0,0,0};
        short8 kn = zero8;
        if (more) {
            int jn = (st + 1) * 64;
            ga = *(const float4*)(vrow + jn + sq * 8);
            gb = *(const float4*)(vrow + jn + sq * 8 + 32);
            if (g == 0) kn = *(const short8*)(kbb + (size_t)(j0 + jn + jw + il) * 8);
            Zn = *(const float4*)(Zb + j0 + jn + jw + 4 * g);
        }

        // S^T: D[j=4g+r][i=il] per i-tile (K pad 8->32)
        f32x4 sv[4];
        #pragma unroll
        for (int it = 0; it < 4; ++it)
            sv[it] = __builtin_amdgcn_mfma_f32_16x16x32_bf16(kf, qf[it], cz, 0, 0, 0);

        float r0 = __builtin_amdgcn_rcpf(Zv.x);
        float r1 = __builtin_amdgcn_rcpf(Zv.y);
        float r2 = __builtin_amdgcn_rcpf(Zv.z);
        float r3 = __builtin_amdgcn_rcpf(Zv.w);

        // P = exp2(s)/Z -> bf16 pairs; these regs ARE the PV B-frags (k=4g+e)
        short4b pf[4];
        #pragma unroll
        for (int it = 0; it < 4; ++it) {
            float p0 = __builtin_amdgcn_exp2f(sv[it][0]) * r0;
            float p1 = __builtin_amdgcn_exp2f(sv[it][1]) * r1;
            float p2 = __builtin_amdgcn_exp2f(sv[it][2]) * r2;
            float p3 = __builtin_amdgcn_exp2f(sv[it][3]) * r3;
            uint2 u;
            u.x = cvt_pk_bf16(p0, p1);
            u.y = cvt_pk_bf16(p2, p3);
            pf[it] = __builtin_bit_cast(short4b, u);
        }

        // PV: acc[c16][i16] += vz[c][wave's 16 j] x P^T  (K=16 MFMA)
        #pragma unroll
        for (int cg = 0; cg < 4; ++cg) {
            int row = cg * 16 + il;
            short4b af = *(short4b*)&vz[cur][row * 64 + ((rslot ^ (row & 7)) * 8) + rbyte];
            #pragma unroll
            for (int it = 0; it < 4; ++it)
                acc[cg][it] = mfma16(af, pf[it], acc[cg][it]);
        }

        if (more) {
            *(float4*)&vz[cur ^ 1][sr * 64 + so0] = ga;
            *(float4*)&vz[cur ^ 1][sr * 64 + so1] = gb;
            kf = kn; Zv = Zn;
        }
        __syncthreads();
    }

    // epilogue: cross-wave reduce via LDS (4 cg rounds), one atomic per elem
    float* red = (float*)vz;                       // 4096 floats
    float* obase = out + (size_t)b * CCH * NPOS + ibase;
    int i_l = tid >> 2, c0 = (tid & 3) * 4;
    #pragma unroll
    for (int cg = 0; cg < 4; ++cg) {
        #pragma unroll
        for (int it = 0; it < 4; ++it)
            *(f32x4*)&red[w * 1024 + (it * 16 + il) * 16 + 4 * g] = acc[cg][it];
        __syncthreads();
        f32x4 sum = *(f32x4*)&red[tid * 4];
        sum += *(f32x4*)&red[1024 + tid * 4];
        sum += *(f32x4*)&red[2048 + tid * 4];
        sum += *(f32x4*)&red[3072 + tid * 4];
        #pragma unroll
        for (int e = 0; e < 4; ++e)
            atomicAdd(obase + (size_t)(cg * 16 + c0 + e) * NPOS + i_l, sum[e]);
        __syncthreads();
    }
}

extern "C" void kernel_launch(void* const* d_in, const int* in_sizes, int n_in,
                              void* d_out, int out_size, void* d_ws, size_t ws_size,
                              hipStream_t stream) {
    const float* X  = (const float*)d_in[0];
    const float* Y  = (const float*)d_in[1];
    const float* Wq = (const float*)d_in[2];
    const float* bq = (const float*)d_in[3];
    const float* Wk = (const float*)d_in[4];
    const float* bk = (const float*)d_in[5];
    const float* Wv = (const float*)d_in[6];
    const float* bv = (const float*)d_in[7];

    char* ws = (char*)d_ws;
    ushort* qb  = (ushort*)(ws);             // 2*9216*8 bf16   = 294912 B
    ushort* kbw = (ushort*)(ws + 294912);    // 294912 B
    ushort* vT  = (ushort*)(ws + 589824);    // 2*64*9216 bf16  = 2359296 B
    float*  Z   = (float*) (ws + 2949120);   // 18432 f32       = 73728 B

    (void)hipMemsetAsync(Z, 0, (size_t)NB * NPOS * sizeof(float), stream);

    qkv_kernel<<<576, 256, 0, stream>>>(X, Y, Wq, bq, Wk, bk, Wv, bv,
                                        qb, kbw, vT, (float*)d_out);
    zpass_kernel<<<dim3(72, 8, NB), 256, 0, stream>>>(qb, kbw, Z);
    pass2_kernel<<<dim3(144, JSPLIT, NB), 256, 0, stream>>>(qb, kbw, vT, Z,
                                                            (float*)d_out);
}